// Round 15
// baseline (131.013 us; speedup 1.0000x reference)
//
#include <hip/hip_runtime.h>
#include <hip/hip_bf16.h>

#define NN      20
#define FF      2764800            // 3*720*1280
#define TK      256                // k-floats per tile per row (1KB burst/row)
#define NROWS   40                 // 20 rows clip2 + 20 rows clip1
#define NTILES  (FF / TK)          // 10800
#define NBLK    256                // 1 block/CU (LDS: 3x40KB triple buffer)
#define NTHREADS 512               // 8 waves

typedef __attribute__((ext_vector_type(8))) short bf16x8;   // 8 bf16 = 4 VGPR
typedef __attribute__((ext_vector_type(4))) float f32x4;

// ws layout (floats): nrep replicas of 440:
//   [rep*440 + 0..399]   cross[i*20+j]
//   [rep*440 + 400..419] q2[i]  (clip2 row sums of squares)
//   [rep*440 + 420..439] q1[j]  (clip1)

__global__ void zero_ws_kernel(float* __restrict__ ws, int n) {
    int i = blockIdx.x * blockDim.x + threadIdx.x;
    if (i < n) ws[i] = 0.0f;
}

static __device__ inline bf16x8 cvt8(float4 lo, float4 hi) {
    union { __hip_bfloat162 h[4]; bf16x8 v; } u;
    u.h[0] = __float22bfloat162_rn(float2{lo.x, lo.y});
    u.h[1] = __float22bfloat162_rn(float2{lo.z, lo.w});
    u.h[2] = __float22bfloat162_rn(float2{hi.x, hi.y});
    u.h[3] = __float22bfloat162_rn(float2{hi.z, hi.w});
    return u.v;
}

// DEPTH EXPERIMENT: 3-deep triple-buffered gload_lds pipeline.
// Per wave: 5 x 1KB bursts per tile; at compute time tiles t+1 and t+2 are
// in flight (10 outstanding) -> counted s_waitcnt vmcnt(10) waits only for
// tile t's own loads. Nominal in-flight per CU = 8 waves x 15KB = 120KB,
// vs ~10KB effective in all prior rounds (Little's-law probe: if delivered
// BW doesn't rise, the ~3.3 TB/s cap is a service-rate limit, not latency).
__global__ __launch_bounds__(NTHREADS, 1) void gram_kernel(
    const float* __restrict__ clip1,
    const float* __restrict__ clip2,
    float* __restrict__ ws,
    int repMask)
{
    __shared__ __align__(16) float s[3][NROWS * TK];   // 3 x 40,960 B

    const int tid  = threadIdx.x;
    const int lane = tid & 63;
    const int wv   = tid >> 6;          // 0..7
    const int sidx = lane & 15;
    const int kq   = lane >> 4;         // 0..3
    const int tj   = wv & 1;            // quadrant col
    const int ti   = (wv >> 1) & 1;     // quadrant row
    const int kh   = wv >> 2;           // K-half: k in [kh*128, kh*128+128)

    // ---- staging: wave wv owns rows 5*wv .. 5*wv+4, one 1KB burst each
    const float* srcp[5];               // per-lane source (swizzled block)
    int ldsoff[5];                      // byte offset of row base in buffer
    #pragma unroll
    for (int ss = 0; ss < 5; ++ss) {
        int r = 5 * wv + ss;
        const float* base = (r < NN) ? (clip2 + (size_t)r * FF)
                                     : (clip1 + (size_t)(r - NN) * FF);
        srcp[ss]   = base + ((lane ^ (r & 7)) << 2);   // logical block lane^(r&7)
        ldsoff[ss] = r * (TK * 4);
    }

    auto stage = [&](int bi, int tile) {
        #pragma unroll
        for (int ss = 0; ss < 5; ++ss) {
            const float* ga = srcp[ss] + (size_t)tile * TK;
            char* la = (char*)&s[bi][0] + ldsoff[ss];
            __builtin_amdgcn_global_load_lds(
                (const __attribute__((address_space(1))) void*)ga,
                (__attribute__((address_space(3))) void*)la, 16, 0, 0);
        }
    };

    // ---- fragment read coordinates
    const int rowA = ti * 16 + sidx;                                  // c2 side
    const int rowB = 20 + tj * 16 + (tj ? (sidx < 4 ? sidx : 3) : sidx); // c1
    const int swzA = rowA & 7;
    const int swzB = rowB & 7;

    f32x4 acc = {0.f, 0.f, 0.f, 0.f};
    float sqr[5] = {0.f, 0.f, 0.f, 0.f, 0.f};

    int t = blockIdx.x;
    stage(0, t);                        // tiles t, t+NBLK always exist (42+/block)
    stage(1, t + NBLK);
    int cur = 0;

    while (t < NTILES) {
        const int t2 = t + 2 * NBLK;
        if (t2 < NTILES)
            stage(cur == 0 ? 2 : (cur == 1 ? 0 : 1), t2);   // buffer (cur+2)%3

        // wait for THIS tile's 5 bursts; keep later tiles' loads in flight
        if (t2 < NTILES)
            asm volatile("s_waitcnt vmcnt(10)" ::: "memory");
        else if (t + NBLK < NTILES)
            asm volatile("s_waitcnt vmcnt(5)" ::: "memory");
        else
            asm volatile("s_waitcnt vmcnt(0)" ::: "memory");
        __builtin_amdgcn_sched_barrier(0);
        __builtin_amdgcn_s_barrier();                 // all waves' rows landed

        const float* buf = &s[cur][0];
        // 4 MFMA over this wave's K-half
        #pragma unroll
        for (int m = 0; m < 4; ++m) {
            const int k0 = kh * 128 + 32 * m;
            const int bA = (k0 >> 2) + 2 * kq;        // 16B-block index
            float4 a0 = *(const float4*)&buf[rowA * TK + (((bA    ) ^ swzA) << 2)];
            float4 a1 = *(const float4*)&buf[rowA * TK + (((bA + 1) ^ swzA) << 2)];
            float4 b0 = *(const float4*)&buf[rowB * TK + (((bA    ) ^ swzB) << 2)];
            float4 b1 = *(const float4*)&buf[rowB * TK + (((bA + 1) ^ swzB) << 2)];
            acc = __builtin_amdgcn_mfma_f32_16x16x32_bf16(
                      cvt8(a0, a1), cvt8(b0, b1), acc, 0, 0, 0);
        }
        // squares: wave reads its own 5 rows linearly (swizzle irrelevant to sum)
        #pragma unroll
        for (int ss = 0; ss < 5; ++ss) {
            float4 v = *(const float4*)&buf[(5 * wv + ss) * TK + (lane << 2)];
            sqr[ss] += v.x * v.x + v.y * v.y + v.z * v.z + v.w * v.w;
        }

        __builtin_amdgcn_s_barrier();   // reads done before iteration t+NBLK
                                        // re-stages this buffer (t+3*NBLK)
        cur = (cur == 2) ? 0 : cur + 1;
        t += NBLK;
    }

    float* wsr = ws + (blockIdx.x & repMask) * 440;

    // cross: C/D layout col=lane&15, row=(lane>>4)*4+reg (m89/m91);
    // two kh-waves per quadrant both atomicAdd their partial K-half.
    #pragma unroll
    for (int r = 0; r < 4; ++r) {
        int i = ti * 16 + kq * 4 + r;
        int j = tj * 16 + sidx;
        if (i < NN && j < NN) atomicAdd(&wsr[i * NN + j], acc[r]);
    }

    // squares: full-wave reduce, one value per owned row
    #pragma unroll
    for (int ss = 0; ss < 5; ++ss) {
        float vq = sqr[ss];
        vq += __shfl_xor(vq, 32);
        vq += __shfl_xor(vq, 16);
        vq += __shfl_xor(vq, 8);
        vq += __shfl_xor(vq, 4);
        vq += __shfl_xor(vq, 2);
        vq += __shfl_xor(vq, 1);
        if (lane == 0) atomicAdd(&wsr[400 + 5 * wv + ss], vq);
    }
}

// Parallel finalize: 256 threads collapse nrep replicas of 440 entries into
// LDS, then 21 threads compute the diagonal means from LDS.
__global__ void finalize_kernel(const float* __restrict__ ws, float* __restrict__ out,
                                int nrep) {
    __shared__ float w[440];
    const int tid = threadIdx.x;

    for (int e = tid; e < 440; e += 256) {
        float s = 0.0f;
        for (int rep = 0; rep < nrep; ++rep)
            s += ws[rep * 440 + e];
        w[e] = s;
    }
    __syncthreads();

    if (tid < 21) {
        int k  = tid - 10;                  // diagonal offset (col - row)
        int a  = k < 0 ? -k : k;
        int i0 = k < 0 ? -k : 0;
        int L  = NN - a;
        const float invF = 1.0f / (float)FF;
        float sum = 0.0f;
        for (int m = 0; m < L; ++m) {
            int i = i0 + m;
            int j = i + k;
            sum += w[400 + i] + w[420 + j] - 2.0f * w[i * NN + j];
        }
        out[tid] = -(sum * invF / (float)L) * 1e13f;
    }
}

extern "C" void kernel_launch(void* const* d_in, const int* in_sizes, int n_in,
                              void* d_out, int out_size, void* d_ws, size_t ws_size,
                              hipStream_t stream) {
    const float* clip1 = (const float*)d_in[0];
    const float* clip2 = (const float*)d_in[1];
    float* out = (float*)d_out;
    float* ws  = (float*)d_ws;

    int nrep = 1;
    while (nrep < 64 && (size_t)(nrep * 2) * 440 * sizeof(float) <= ws_size)
        nrep *= 2;

    int nz = nrep * 440;
    zero_ws_kernel<<<(nz + 255) / 256, 256, 0, stream>>>(ws, nz);
    gram_kernel<<<NBLK, NTHREADS, 0, stream>>>(clip1, clip2, ws, nrep - 1);
    finalize_kernel<<<1, 256, 0, stream>>>(ws, out, nrep);
}

// Round 16
// 119.986 us; speedup vs baseline: 1.0919x; 1.0919x over previous
//
#include <hip/hip_runtime.h>
#include <hip/hip_bf16.h>

#define NN      20
#define FF      2764800            // 3*720*1280
#define TK      256                // k-floats per tile per row (1KB burst/row)
#define NROWS   40                 // 20 rows clip2 + 20 rows clip1
#define NTILES  (FF / TK)          // 10800
#define NBLK    512                // 2 blocks/CU * 256 CUs (LDS: 2x40KB)
#define NTHREADS 512               // 8 waves

typedef __attribute__((ext_vector_type(8))) short bf16x8;   // 8 bf16 = 4 VGPR
typedef __attribute__((ext_vector_type(4))) float f32x4;

// ws layout (floats): nrep replicas of 440:
//   [rep*440 + 0..399]   cross[i*20+j]
//   [rep*440 + 400..419] q2[i]  (clip2 row sums of squares)
//   [rep*440 + 420..439] q1[j]  (clip1)

__global__ void zero_ws_kernel(float* __restrict__ ws, int n) {
    int i = blockIdx.x * blockDim.x + threadIdx.x;
    if (i < n) ws[i] = 0.0f;
}

static __device__ inline bf16x8 cvt8(float4 lo, float4 hi) {
    union { __hip_bfloat162 h[4]; bf16x8 v; } u;
    u.h[0] = __float22bfloat162_rn(float2{lo.x, lo.y});
    u.h[1] = __float22bfloat162_rn(float2{lo.z, lo.w});
    u.h[2] = __float22bfloat162_rn(float2{hi.x, hi.y});
    u.h[3] = __float22bfloat162_rn(float2{hi.z, hi.w});
    return u.v;
}

// LDS tile: 40 rows x 256 floats (1KB/row), linear rows. 16B-block m of row r
// holds global block m ^ (r&7) (source pre-swizzled; involution), making all
// fragment ds_read_b128 uniformly distributed over bank positions.
// Staging: ONE global_load_lds per row = 64 lanes x 16B = 1KB contiguous.
// Pipeline: double buffer, counted vmcnt(5) + raw s_barrier (prefetch stays
// in flight across barriers; 5 gload_lds per wave per tile, uniform).
// This configuration measured best (bench 120.75us, R12); depth-3 and other
// variants were null or regressed -> delivered ~3.8 TB/s reads = the chip's
// measured streaming-read service rate (m13 copy = 3.15 read + 3.15 write).
__global__ __launch_bounds__(NTHREADS, 4) void gram_kernel(
    const float* __restrict__ clip1,
    const float* __restrict__ clip2,
    float* __restrict__ ws,
    int repMask)
{
    __shared__ __align__(16) float s[2][NROWS * TK];   // 2 x 40,960 B

    const int tid  = threadIdx.x;
    const int lane = tid & 63;
    const int wv   = tid >> 6;          // 0..7
    const int sidx = lane & 15;
    const int kq   = lane >> 4;         // 0..3
    const int tj   = wv & 1;            // quadrant col
    const int ti   = (wv >> 1) & 1;     // quadrant row
    const int kh   = wv >> 2;           // K-half: k in [kh*128, kh*128+128)

    // ---- staging: wave wv owns rows 5*wv .. 5*wv+4, one 1KB burst each
    const float* srcp[5];               // per-lane source (swizzled block)
    int ldsoff[5];                      // byte offset of row base in buffer
    #pragma unroll
    for (int ss = 0; ss < 5; ++ss) {
        int r = 5 * wv + ss;
        const float* base = (r < NN) ? (clip2 + (size_t)r * FF)
                                     : (clip1 + (size_t)(r - NN) * FF);
        srcp[ss]   = base + ((lane ^ (r & 7)) << 2);   // logical block lane^(r&7)
        ldsoff[ss] = r * (TK * 4);
    }

    auto stage = [&](int bi, int tile) {
        #pragma unroll
        for (int ss = 0; ss < 5; ++ss) {
            const float* ga = srcp[ss] + (size_t)tile * TK;
            char* la = (char*)&s[bi][0] + ldsoff[ss];
            __builtin_amdgcn_global_load_lds(
                (const __attribute__((address_space(1))) void*)ga,
                (__attribute__((address_space(3))) void*)la, 16, 0, 0);
        }
    };

    // ---- fragment read coordinates
    const int rowA = ti * 16 + sidx;                                  // c2 side
    const int rowB = 20 + tj * 16 + (tj ? (sidx < 4 ? sidx : 3) : sidx); // c1
    const int swzA = rowA & 7;
    const int swzB = rowB & 7;

    f32x4 acc = {0.f, 0.f, 0.f, 0.f};
    float sqr[5] = {0.f, 0.f, 0.f, 0.f, 0.f};

    int t = blockIdx.x;
    stage(0, t);
    int cur = 0;

    while (t < NTILES) {
        const int tn = t + NBLK;
        if (tn < NTILES) {
            stage(cur ^ 1, tn);                       // prefetch next tile
            asm volatile("s_waitcnt vmcnt(5)" ::: "memory");  // own tile-t loads done
        } else {
            asm volatile("s_waitcnt vmcnt(0)" ::: "memory");
        }
        __builtin_amdgcn_sched_barrier(0);
        __builtin_amdgcn_s_barrier();                 // all waves' staging done

        const float* buf = &s[cur][0];
        // 4 MFMA over this wave's K-half
        #pragma unroll
        for (int m = 0; m < 4; ++m) {
            const int k0 = kh * 128 + 32 * m;
            const int bA = (k0 >> 2) + 2 * kq;        // 16B-block index
            float4 a0 = *(const float4*)&buf[rowA * TK + (((bA    ) ^ swzA) << 2)];
            float4 a1 = *(const float4*)&buf[rowA * TK + (((bA + 1) ^ swzA) << 2)];
            float4 b0 = *(const float4*)&buf[rowB * TK + (((bA    ) ^ swzB) << 2)];
            float4 b1 = *(const float4*)&buf[rowB * TK + (((bA + 1) ^ swzB) << 2)];
            acc = __builtin_amdgcn_mfma_f32_16x16x32_bf16(
                      cvt8(a0, a1), cvt8(b0, b1), acc, 0, 0, 0);
        }
        // squares: wave reads its own 5 rows linearly (swizzle irrelevant to sum)
        #pragma unroll
        for (int ss = 0; ss < 5; ++ss) {
            float4 v = *(const float4*)&buf[(5 * wv + ss) * TK + (lane << 2)];
            sqr[ss] += v.x * v.x + v.y * v.y + v.z * v.z + v.w * v.w;
        }

        __builtin_amdgcn_s_barrier();                 // reads done before overwrite
        cur ^= 1;
        t = tn;
    }

    float* wsr = ws + (blockIdx.x & repMask) * 440;

    // cross: C/D layout col=lane&15, row=(lane>>4)*4+reg (m89/m91);
    // two kh-waves per quadrant both atomicAdd their partial K-half.
    #pragma unroll
    for (int r = 0; r < 4; ++r) {
        int i = ti * 16 + kq * 4 + r;
        int j = tj * 16 + sidx;
        if (i < NN && j < NN) atomicAdd(&wsr[i * NN + j], acc[r]);
    }

    // squares: full-wave reduce, one value per owned row
    #pragma unroll
    for (int ss = 0; ss < 5; ++ss) {
        float vq = sqr[ss];
        vq += __shfl_xor(vq, 32);
        vq += __shfl_xor(vq, 16);
        vq += __shfl_xor(vq, 8);
        vq += __shfl_xor(vq, 4);
        vq += __shfl_xor(vq, 2);
        vq += __shfl_xor(vq, 1);
        if (lane == 0) atomicAdd(&wsr[400 + 5 * wv + ss], vq);
    }
}

// Parallel finalize: 256 threads collapse nrep replicas of 440 entries into
// LDS, then 21 threads compute the diagonal means from LDS.
__global__ void finalize_kernel(const float* __restrict__ ws, float* __restrict__ out,
                                int nrep) {
    __shared__ float w[440];
    const int tid = threadIdx.x;

    for (int e = tid; e < 440; e += 256) {
        float s = 0.0f;
        for (int rep = 0; rep < nrep; ++rep)
            s += ws[rep * 440 + e];
        w[e] = s;
    }
    __syncthreads();

    if (tid < 21) {
        int k  = tid - 10;                  // diagonal offset (col - row)
        int a  = k < 0 ? -k : k;
        int i0 = k < 0 ? -k : 0;
        int L  = NN - a;
        const float invF = 1.0f / (float)FF;
        float sum = 0.0f;
        for (int m = 0; m < L; ++m) {
            int i = i0 + m;
            int j = i + k;
            sum += w[400 + i] + w[420 + j] - 2.0f * w[i * NN + j];
        }
        out[tid] = -(sum * invF / (float)L) * 1e13f;
    }
}

extern "C" void kernel_launch(void* const* d_in, const int* in_sizes, int n_in,
                              void* d_out, int out_size, void* d_ws, size_t ws_size,
                              hipStream_t stream) {
    const float* clip1 = (const float*)d_in[0];
    const float* clip2 = (const float*)d_in[1];
    float* out = (float*)d_out;
    float* ws  = (float*)d_ws;

    int nrep = 1;
    while (nrep < 64 && (size_t)(nrep * 2) * 440 * sizeof(float) <= ws_size)
        nrep *= 2;

    int nz = nrep * 440;
    zero_ws_kernel<<<(nz + 255) / 256, 256, 0, stream>>>(ws, nz);
    gram_kernel<<<NBLK, NTHREADS, 0, stream>>>(clip1, clip2, ws, nrep - 1);
    finalize_kernel<<<1, 256, 0, stream>>>(ws, out, nrep);
}